// Round 7
// baseline (222.193 us; speedup 1.0000x reference)
//
#include <hip/hip_runtime.h>
#include <hip/hip_bf16.h>
#include <stdint.h>

// B=2, N=2048, H=1024, NH=16, DH=64.
// SCALE = H^-0.5 = 1/32; softmax computed in exp2 domain, so Q is
// pre-scaled by SCALE*log2(e) at the GEMM epilogue.
#define B_ 2
#define N_ 2048
#define H_ 1024
#define NH_ 16
#define DH_ 64
#define E_ 3072
#define M_ 4096
#define K_ 1024
#define QSCALE2_ 0.0450842200277786f   /* (1/32) * log2(e) */
#define THR2_    11.5415603f           /* defer-max: 8 * log2(e) */

typedef unsigned short ushort_t;
typedef short bf16x8 __attribute__((ext_vector_type(8)));
typedef float f32x4 __attribute__((ext_vector_type(4)));
typedef ushort_t ushort8 __attribute__((ext_vector_type(8)));
typedef ushort_t ushort4v __attribute__((ext_vector_type(4)));
typedef float float4v __attribute__((ext_vector_type(4)));

// HW convert via plain cast (m240: compiles to hw cvt path — do not hand-roll
// inline asm).  memcpy punning avoids union-with-nontrivial-ctor issues.
static __device__ __forceinline__ ushort_t f2bf(float f) {
  __hip_bfloat16 h = __float2bfloat16(f);
  ushort_t u;
  __builtin_memcpy(&u, &h, sizeof(u));
  return u;
}
static __device__ __forceinline__ uint32_t pk2bf(float lo, float hi) {
  return (uint32_t)f2bf(lo) | ((uint32_t)f2bf(hi) << 16);
}
static __device__ __forceinline__ float max3f(float a, float b, float c) {
  return fmaxf(fmaxf(a, b), c);  // clang fuses to v_max3_f32
}

#define GLOAD_LDS16(g, l)                                                   \
  __builtin_amdgcn_global_load_lds(                                         \
      (const __attribute__((address_space(1))) void*)(g),                   \
      (__attribute__((address_space(3))) void*)(l), 16, 0, 0)

// ---------------------------------------------------------------- convert
// fp32 -> bf16 for X [4096,1024] and W [3072,1024]
__global__ void convert_kernel(const float* __restrict__ X,
                               const float* __restrict__ W,
                               ushort_t* __restrict__ Xb,
                               ushort_t* __restrict__ Wb) {
  const int nx4 = (M_ * K_) / 4;
  int i = blockIdx.x * blockDim.x + threadIdx.x;
  if (i < nx4) {
    float4v v = ((const float4v*)X)[i];
    ushort4v o;
    o[0] = f2bf(v[0]); o[1] = f2bf(v[1]); o[2] = f2bf(v[2]); o[3] = f2bf(v[3]);
    ((ushort4v*)Xb)[i] = o;
  } else {
    int j = i - nx4;  // grid sized exactly (nx4 + nw4 threads)
    float4v v = ((const float4v*)W)[j];
    ushort4v o;
    o[0] = f2bf(v[0]); o[1] = f2bf(v[1]); o[2] = f2bf(v[2]); o[3] = f2bf(v[3]);
    ((ushort4v*)Wb)[j] = o;
  }
}

// ---------------------------------------------------------------- QKV GEMM
// out[m,e] = sum_k X[m,k]*W[e,k].  m97 structure (128x128, BK=64, 4 waves,
// global_load_lds w16).  Epilogue: Q pre-scaled by SCALE*log2e -> [bh][n][d];
// K -> [bh][n][d]; V written TRANSPOSED -> VT [bh][d][n] with 8B vec stores
// (j indexes 4 consecutive n).  1-D grid 768, chunked XCD swizzle (T1).
__global__ void gemm_qkv(const ushort_t* __restrict__ Xb,
                         const ushort_t* __restrict__ Wb,
                         ushort_t* __restrict__ Qw,
                         ushort_t* __restrict__ Kw,
                         ushort_t* __restrict__ VTw) {
  __shared__ ushort_t lds_a[128 * 64];
  __shared__ ushort_t lds_b[128 * 64];
  const int tid = threadIdx.x;
  const int lane = tid & 63;
  const int w = tid >> 6;
  const int g = lane >> 4;
  const int l15 = lane & 15;
  const int wid = blockIdx.x;
  const int logical = (wid & 7) * 96 + (wid >> 3);  // XCD-chunked (bijective)
  const int m0 = (logical / 24) * 128;
  const int e0 = (logical % 24) * 128;
  const int wr = w >> 1, wc = w & 1;

  f32x4 zero = {0.f, 0.f, 0.f, 0.f};
  f32x4 acc[4][4];
#pragma unroll
  for (int mi = 0; mi < 4; ++mi)
#pragma unroll
    for (int ni = 0; ni < 4; ++ni) acc[mi][ni] = zero;

  for (int kt = 0; kt < K_ / 64; ++kt) {
    const int k0 = kt * 64;
#pragma unroll
    for (int i = 0; i < 4; ++i) {
      int chunk = i * 4 + w;           // wave-uniform LDS dest
      int c = chunk * 64 + lane;       // 0..1023 16B-chunks
      int row = c >> 3;
      int col = (c & 7) * 8;
      GLOAD_LDS16(Xb + (size_t)(m0 + row) * K_ + k0 + col, lds_a + chunk * 512);
      GLOAD_LDS16(Wb + (size_t)(e0 + row) * K_ + k0 + col, lds_b + chunk * 512);
    }
    __syncthreads();
#pragma unroll
    for (int ks = 0; ks < 2; ++ks) {
      bf16x8 af[4], bfr[4];
#pragma unroll
      for (int mi = 0; mi < 4; ++mi)
        af[mi] = *(const bf16x8*)(lds_a + (wr * 64 + mi * 16 + l15) * 64 + ks * 32 + g * 8);
#pragma unroll
      for (int ni = 0; ni < 4; ++ni)
        bfr[ni] = *(const bf16x8*)(lds_b + (wc * 64 + ni * 16 + l15) * 64 + ks * 32 + g * 8);
#pragma unroll
      for (int mi = 0; mi < 4; ++mi)
#pragma unroll
        for (int ni = 0; ni < 4; ++ni)
          acc[mi][ni] = __builtin_amdgcn_mfma_f32_16x16x32_bf16(af[mi], bfr[ni], acc[mi][ni], 0, 0, 0);
    }
    __syncthreads();
  }

  // epilogue: C/D layout col=lane&15, row=(lane>>4)*4+j  [verified m89/m91]
  // kidx block-uniform (128-wide e-block never spans a 1024 boundary).
  const int kidx = e0 >> 10;
  if (kidx == 2) {
    // V -> VT [bh][d][n], 4 consecutive n per thread -> 8B stores
#pragma unroll
    for (int ni = 0; ni < 4; ++ni) {
      int e = e0 + wc * 64 + ni * 16 + l15;
      int h = (e >> 6) & 15;
      int d = e & 63;
#pragma unroll
      for (int mi = 0; mi < 4; ++mi) {
        int m = m0 + wr * 64 + mi * 16 + g * 4;
        int b = m >> 11;
        int n = m & (N_ - 1);
        ushort4v pk;
#pragma unroll
        for (int j = 0; j < 4; ++j) pk[j] = f2bf(acc[mi][ni][j]);
        *(ushort4v*)(VTw + ((size_t)(b * NH_ + h) * DH_ + d) * N_ + n) = pk;
      }
    }
  } else {
    ushort_t* dst = (kidx == 0) ? Qw : Kw;
    const float sc = (kidx == 0) ? QSCALE2_ : 1.0f;
#pragma unroll
    for (int ni = 0; ni < 4; ++ni) {
      int e = e0 + wc * 64 + ni * 16 + l15;
      int h = (e >> 6) & 15;
      int d = e & 63;
#pragma unroll
      for (int mi = 0; mi < 4; ++mi) {
#pragma unroll
        for (int j = 0; j < 4; ++j) {
          int m = m0 + wr * 64 + mi * 16 + g * 4 + j;
          int b = m >> 11;
          int n = m & (N_ - 1);
          dst[(size_t)((b * NH_ + h) * N_ + n) * DH_ + d] = f2bf(acc[mi][ni][j] * sc);
        }
      }
    }
  }
}

// ---------------------------------------------------------------- attention
// Block = (b,h) x 128 q-rows; 2 waves x 64 q (4 sub-tiles of 16) — doubles
// arithmetic intensity vs 4x32: K/V LDS reads per q-row halved (modeled
// LDS-throughput bound).  Swapped QK^T (S^T = K.Q^T, Q pre-scaled by
// SCALE*log2e).  Mask folded into Q-load (masked row -> qf=0 -> uniform
// softmax == reference semantics; kills per-iter cndmask).  K/VT
// XOR-swizzled (rule #21: linear gload_lds dest + inverse-swz source + swz
// read; all reads resolve to <=2 lanes/bank = free).  Double-buffered
// 2-phase.  exp2-domain online softmax w/ defer-max (T13), max3 tree (T17),
// setprio (T5).  Grid 512, chunked XCD swizzle (T1).
__global__ __launch_bounds__(128, 1)
void attn_kernel(const ushort_t* __restrict__ Qw,
                 const ushort_t* __restrict__ Kw,
                 const ushort_t* __restrict__ VTw,
                 const int* __restrict__ amask,
                 float* __restrict__ out) {
  // dbuf K(4096)+VT(4096) x2 = 16384 ush; P = 2w*64*72 = 9216 ush (51200 B)
  __shared__ ushort_t smem[16384 + 9216];
  ushort_t* lds_p = smem + 16384;

  const int tid = threadIdx.x;
  const int lane = tid & 63;
  const int w = tid >> 6;               // 0..1
  const int g = lane >> 4;
  const int l15 = lane & 15;
  const int wid = blockIdx.x;
  const int logical = (wid & 7) * 64 + (wid >> 3);  // XCD-chunked (bijective)
  const int bh = logical >> 4;
  const int b = bh >> 4, h = bh & 15;
  const int q0 = (logical & 15) * 128;

  const size_t base_nd = (size_t)bh * N_ * DH_;  // Q,K [n][64]
  const size_t base_dn = (size_t)bh * DH_ * N_;  // VT  [64][n]

  // per-wave q rows: q = q0 + w*64 + qi*16 + l15   (qi = 0..3)
  const bf16x8 qzero = {0, 0, 0, 0, 0, 0, 0, 0};
  bf16x8 qf[4][2];
#pragma unroll
  for (int qi = 0; qi < 4; ++qi) {
    int q = q0 + w * 64 + qi * 16 + l15;
    int mq = amask[b * N_ + q];  // faithful query-row mask
#pragma unroll
    for (int ks = 0; ks < 2; ++ks) {
      bf16x8 v = *(const bf16x8*)(Qw + base_nd + (size_t)q * DH_ + ks * 32 + g * 8);
      qf[qi][ks] = mq ? v : qzero;     // masked row -> all scores equal ->
    }                                  // uniform softmax == reference
  }

  // staging lane geometry (swizzled source, rule #21):
  const int st_r = (lane >> 3);              // row-within-chunk 0..7
  const int st_s = (lane & 7) ^ st_r;        // swizzled 16B col-slot

  f32x4 zero = {0.f, 0.f, 0.f, 0.f};
  f32x4 oacc[4][4];
#pragma unroll
  for (int qi = 0; qi < 4; ++qi)
#pragma unroll
    for (int df = 0; df < 4; ++df) oacc[qi][df] = zero;
  float m_run[4] = {-3.0e38f, -3.0e38f, -3.0e38f, -3.0e38f};
  float l_run[4] = {0.0f, 0.0f, 0.0f, 0.0f};

  const int NT = N_ / 64;

  // prologue: stage tile 0 into buf 0 (8 chunks per tile, 4 per wave)
  {
#pragma unroll
    for (int i = 0; i < 4; ++i) {
      int chunk = w * 4 + i;
      int r = chunk * 8 + st_r;
      GLOAD_LDS16(Kw + base_nd + (size_t)r * DH_ + st_s * 8, smem + chunk * 512);
      GLOAD_LDS16(VTw + base_dn + (size_t)r * N_ + st_s * 8, smem + 4096 + chunk * 512);
    }
  }
  __syncthreads();

  for (int it = 0; it < NT; ++it) {
    const int cur = it & 1;
    ushort_t* lk = smem + cur * 8192;
    ushort_t* lv = smem + 4096 + cur * 8192;

    // prefetch next tile into the other buffer (overlaps with this compute)
    if (it + 1 < NT) {
      const int kv0n = (it + 1) * 64;
      ushort_t* nk = smem + (cur ^ 1) * 8192;
      ushort_t* nv = nk + 4096;
#pragma unroll
      for (int i = 0; i < 4; ++i) {
        int chunk = w * 4 + i;
        int r = chunk * 8 + st_r;
        GLOAD_LDS16(Kw + base_nd + (size_t)(kv0n + r) * DH_ + st_s * 8, nk + chunk * 512);
        GLOAD_LDS16(VTw + base_dn + (size_t)r * N_ + kv0n + st_s * 8, nv + chunk * 512);
      }
    }

    // ---- QK^T: S^T = K . Q^T  (each K-frag read feeds 4 qi MFMAs)
    f32x4 sacc[4][4];
#pragma unroll
    for (int qi = 0; qi < 4; ++qi)
#pragma unroll
      for (int kvf = 0; kvf < 4; ++kvf) sacc[qi][kvf] = zero;
    __builtin_amdgcn_s_setprio(1);
#pragma unroll
    for (int ks = 0; ks < 2; ++ks) {
#pragma unroll
      for (int kvf = 0; kvf < 4; ++kvf) {
        bf16x8 a = *(const bf16x8*)(lk + (kvf * 16 + l15) * 64 +
                                    (((ks * 4 + g) ^ (l15 & 7)) * 8));
#pragma unroll
        for (int qi = 0; qi < 4; ++qi)
          sacc[qi][kvf] = __builtin_amdgcn_mfma_f32_16x16x32_bf16(a, qf[qi][ks], sacc[qi][kvf], 0, 0, 0);
      }
    }
    __builtin_amdgcn_s_setprio(0);

    // ---- exp2-domain online softmax (kv reduce = 2 shfl_xor; defer-max)
    ushort_t* pw = lds_p + w * (64 * 72);
#pragma unroll
    for (int qi = 0; qi < 4; ++qi) {
      float a0 = max3f(sacc[qi][0][0], sacc[qi][0][1], sacc[qi][0][2]);
      float a1 = max3f(sacc[qi][0][3], sacc[qi][1][0], sacc[qi][1][1]);
      float a2 = max3f(sacc[qi][1][2], sacc[qi][1][3], sacc[qi][2][0]);
      float a3 = max3f(sacc[qi][2][1], sacc[qi][2][2], sacc[qi][2][3]);
      float a4 = max3f(sacc[qi][3][0], sacc[qi][3][1], sacc[qi][3][2]);
      float tm = fmaxf(max3f(a0, a1, a2), max3f(a3, a4, sacc[qi][3][3]));
      tm = fmaxf(tm, __shfl_xor(tm, 16));
      tm = fmaxf(tm, __shfl_xor(tm, 32));

      if (__any(tm > m_run[qi] + THR2_)) {   // defer-max: rescale rarely
        float m_new = fmaxf(m_run[qi], tm);
        float alpha = exp2f(m_run[qi] - m_new);
        l_run[qi] *= alpha;
#pragma unroll
        for (int df = 0; df < 4; ++df)
#pragma unroll
          for (int j = 0; j < 4; ++j) oacc[qi][df][j] *= alpha;
        m_run[qi] = m_new;
      }

      float p[16];
#pragma unroll
      for (int kvf = 0; kvf < 4; ++kvf)
#pragma unroll
        for (int j = 0; j < 4; ++j)
          p[kvf * 4 + j] = exp2f(sacc[qi][kvf][j] - m_run[qi]);
      float t0 = (p[0] + p[1]) + (p[2] + p[3]);
      float t1 = (p[4] + p[5]) + (p[6] + p[7]);
      float t2 = (p[8] + p[9]) + (p[10] + p[11]);
      float t3 = (p[12] + p[13]) + (p[14] + p[15]);
      float ps = (t0 + t1) + (t2 + t3);
      ps += __shfl_xor(ps, 16);
      ps += __shfl_xor(ps, 32);
      l_run[qi] += ps;

      // P -> wave-private LDS  [q64][kv 72-padded]
#pragma unroll
      for (int kvf = 0; kvf < 4; ++kvf) {
#pragma unroll
        for (int jj = 0; jj < 2; ++jj) {
          *(uint32_t*)(pw + (qi * 16 + l15) * 72 + kvf * 16 + g * 4 + jj * 2) =
              pk2bf(p[kvf * 4 + jj * 2], p[kvf * 4 + jj * 2 + 1]);
        }
      }
    }

    // ---- PV: O^T += VT . P^T  (each VT-frag read feeds 4 qi MFMAs)
    __builtin_amdgcn_s_setprio(1);
#pragma unroll
    for (int ks = 0; ks < 2; ++ks) {
      bf16x8 pb[4];
#pragma unroll
      for (int qi = 0; qi < 4; ++qi)
        pb[qi] = *(const bf16x8*)(pw + (qi * 16 + l15) * 72 + ks * 32 + g * 8);
#pragma unroll
      for (int df = 0; df < 4; ++df) {
        bf16x8 a = *(const bf16x8*)(lv + (df * 16 + l15) * 64 +
                                    (((ks * 4 + g) ^ (l15 & 7)) * 8));
#pragma unroll
        for (int qi = 0; qi < 4; ++qi)
          oacc[qi][df] = __builtin_amdgcn_mfma_f32_16x16x32_bf16(a, pb[qi], oacc[qi][df], 0, 0, 0);
      }
    }
    __builtin_amdgcn_s_setprio(0);
    __syncthreads();  // drains prefetch vmcnt + protects buffers
  }

  // epilogue: O^T/l -> LDS [q128][68] f32 -> coalesced global
  // (safe: loop-end __syncthreads ensures all waves finished P reads)
  float inv[4];
#pragma unroll
  for (int qi = 0; qi < 4; ++qi) inv[qi] = 1.0f / l_run[qi];
  float* osm = (float*)smem;
#pragma unroll
  for (int qi = 0; qi < 4; ++qi)
#pragma unroll
    for (int df = 0; df < 4; ++df)
#pragma unroll
      for (int j = 0; j < 4; ++j)
        osm[(w * 64 + qi * 16 + l15) * 68 + df * 16 + g * 4 + j] = oacc[qi][df][j] * inv[qi];
  __syncthreads();
  // 128 threads, 128 rows: 4 passes of 32 rows; 4 lanes cover one row
  int d0 = (tid & 3) * 16;
#pragma unroll
  for (int rr = 0; rr < 4; ++rr) {
    int ql = rr * 32 + (tid >> 2);
    float* dst = out + ((size_t)(b * N_ + q0 + ql)) * H_ + h * DH_ + d0;
#pragma unroll
    for (int jj = 0; jj < 4; ++jj) {
      float4v v;
#pragma unroll
      for (int k = 0; k < 4; ++k) v[k] = osm[ql * 68 + d0 + jj * 4 + k];
      *(float4v*)(dst + jj * 4) = v;
    }
  }
}

// ---------------------------------------------------------------- launch
extern "C" void kernel_launch(void* const* d_in, const int* in_sizes, int n_in,
                              void* d_out, int out_size, void* d_ws, size_t ws_size,
                              hipStream_t stream) {
  const float* X = (const float*)d_in[0];
  const int* amask = (const int*)d_in[1];
  const float* Wq = (const float*)d_in[2];
  float* out = (float*)d_out;
  char* ws = (char*)d_ws;
  // ws layout (bytes): Xb 8M | Wb 6M | Q 8M | K 8M | VT 8M  = 38MB total
  ushort_t* Xb  = (ushort_t*)(ws);
  ushort_t* Wb  = (ushort_t*)(ws + 8388608);
  ushort_t* Qw  = (ushort_t*)(ws + 14680064);
  ushort_t* Kw  = (ushort_t*)(ws + 23068672);
  ushort_t* VTw = (ushort_t*)(ws + 31457280);

  convert_kernel<<<7168, 256, 0, stream>>>(X, Wq, Xb, Wb);
  gemm_qkv<<<768, 256, 0, stream>>>(Xb, Wb, Qw, Kw, VTw);
  attn_kernel<<<512, 128, 0, stream>>>(Qw, Kw, VTw, amask, out);
}

// Round 9
// 195.463 us; speedup vs baseline: 1.1368x; 1.1368x over previous
//
#include <hip/hip_runtime.h>
#include <hip/hip_bf16.h>
#include <stdint.h>

// B=2, N=2048, H=1024, NH=16, DH=64.
// SCALE = H^-0.5 = 1/32; softmax computed in exp2 domain, so Q is
// pre-scaled by SCALE*log2(e) at the GEMM epilogue.
#define B_ 2
#define N_ 2048
#define H_ 1024
#define NH_ 16
#define DH_ 64
#define E_ 3072
#define M_ 4096
#define K_ 1024
#define QSCALE2_ 0.0450842200277786f   /* (1/32) * log2(e) */
#define THR2_    11.5415603f           /* defer-max: 8 * log2(e) */

typedef unsigned short ushort_t;
typedef short bf16x8 __attribute__((ext_vector_type(8)));
typedef float f32x4 __attribute__((ext_vector_type(4)));
typedef ushort_t ushort8 __attribute__((ext_vector_type(8)));
typedef ushort_t ushort4v __attribute__((ext_vector_type(4)));
typedef float float4v __attribute__((ext_vector_type(4)));
typedef uint32_t uint2v __attribute__((ext_vector_type(2)));

// HW convert via plain cast (m240: compiles to hw cvt path — do not hand-roll
// inline asm).  memcpy punning avoids union-with-nontrivial-ctor issues.
static __device__ __forceinline__ ushort_t f2bf(float f) {
  __hip_bfloat16 h = __float2bfloat16(f);
  ushort_t u;
  __builtin_memcpy(&u, &h, sizeof(u));
  return u;
}
static __device__ __forceinline__ uint32_t pk2bf(float lo, float hi) {
  return (uint32_t)f2bf(lo) | ((uint32_t)f2bf(hi) << 16);
}
static __device__ __forceinline__ float max3f(float a, float b, float c) {
  return fmaxf(fmaxf(a, b), c);  // clang fuses to v_max3_f32
}

#define GLOAD_LDS16(g, l)                                                   \
  __builtin_amdgcn_global_load_lds(                                         \
      (const __attribute__((address_space(1))) void*)(g),                   \
      (__attribute__((address_space(3))) void*)(l), 16, 0, 0)

// ---------------------------------------------------------------- convert
// fp32 -> bf16 for X [4096,1024] and W [3072,1024]
__global__ void convert_kernel(const float* __restrict__ X,
                               const float* __restrict__ W,
                               ushort_t* __restrict__ Xb,
                               ushort_t* __restrict__ Wb) {
  const int nx4 = (M_ * K_) / 4;
  int i = blockIdx.x * blockDim.x + threadIdx.x;
  if (i < nx4) {
    float4v v = ((const float4v*)X)[i];
    ushort4v o;
    o[0] = f2bf(v[0]); o[1] = f2bf(v[1]); o[2] = f2bf(v[2]); o[3] = f2bf(v[3]);
    ((ushort4v*)Xb)[i] = o;
  } else {
    int j = i - nx4;  // grid sized exactly (nx4 + nw4 threads)
    float4v v = ((const float4v*)W)[j];
    ushort4v o;
    o[0] = f2bf(v[0]); o[1] = f2bf(v[1]); o[2] = f2bf(v[2]); o[3] = f2bf(v[3]);
    ((ushort4v*)Wb)[j] = o;
  }
}

// ---------------------------------------------------------------- QKV GEMM
// out[m,e] = sum_k X[m,k]*W[e,k].  m97 structure (128x128, BK=64, 4 waves,
// global_load_lds w16).  Epilogue: Q pre-scaled by SCALE*log2e -> [bh][n][d];
// K -> [bh][n][d]; V written TRANSPOSED -> VT [bh][d][n] with 8B vec stores
// (j indexes 4 consecutive n).  1-D grid 768, chunked XCD swizzle (T1).
__global__ void gemm_qkv(const ushort_t* __restrict__ Xb,
                         const ushort_t* __restrict__ Wb,
                         ushort_t* __restrict__ Qw,
                         ushort_t* __restrict__ Kw,
                         ushort_t* __restrict__ VTw) {
  __shared__ ushort_t lds_a[128 * 64];
  __shared__ ushort_t lds_b[128 * 64];
  const int tid = threadIdx.x;
  const int lane = tid & 63;
  const int w = tid >> 6;
  const int g = lane >> 4;
  const int l15 = lane & 15;
  const int wid = blockIdx.x;
  const int logical = (wid & 7) * 96 + (wid >> 3);  // XCD-chunked (bijective)
  const int m0 = (logical / 24) * 128;
  const int e0 = (logical % 24) * 128;
  const int wr = w >> 1, wc = w & 1;

  f32x4 zero = {0.f, 0.f, 0.f, 0.f};
  f32x4 acc[4][4];
#pragma unroll
  for (int mi = 0; mi < 4; ++mi)
#pragma unroll
    for (int ni = 0; ni < 4; ++ni) acc[mi][ni] = zero;

  for (int kt = 0; kt < K_ / 64; ++kt) {
    const int k0 = kt * 64;
#pragma unroll
    for (int i = 0; i < 4; ++i) {
      int chunk = i * 4 + w;           // wave-uniform LDS dest
      int c = chunk * 64 + lane;       // 0..1023 16B-chunks
      int row = c >> 3;
      int col = (c & 7) * 8;
      GLOAD_LDS16(Xb + (size_t)(m0 + row) * K_ + k0 + col, lds_a + chunk * 512);
      GLOAD_LDS16(Wb + (size_t)(e0 + row) * K_ + k0 + col, lds_b + chunk * 512);
    }
    __syncthreads();
#pragma unroll
    for (int ks = 0; ks < 2; ++ks) {
      bf16x8 af[4], bfr[4];
#pragma unroll
      for (int mi = 0; mi < 4; ++mi)
        af[mi] = *(const bf16x8*)(lds_a + (wr * 64 + mi * 16 + l15) * 64 + ks * 32 + g * 8);
#pragma unroll
      for (int ni = 0; ni < 4; ++ni)
        bfr[ni] = *(const bf16x8*)(lds_b + (wc * 64 + ni * 16 + l15) * 64 + ks * 32 + g * 8);
#pragma unroll
      for (int mi = 0; mi < 4; ++mi)
#pragma unroll
        for (int ni = 0; ni < 4; ++ni)
          acc[mi][ni] = __builtin_amdgcn_mfma_f32_16x16x32_bf16(af[mi], bfr[ni], acc[mi][ni], 0, 0, 0);
    }
    __syncthreads();
  }

  // epilogue: C/D layout col=lane&15, row=(lane>>4)*4+j  [verified m89/m91]
  // kidx block-uniform (128-wide e-block never spans a 1024 boundary).
  const int kidx = e0 >> 10;
  if (kidx == 2) {
    // V -> VT [bh][d][n], 4 consecutive n per thread -> 8B stores
#pragma unroll
    for (int ni = 0; ni < 4; ++ni) {
      int e = e0 + wc * 64 + ni * 16 + l15;
      int h = (e >> 6) & 15;
      int d = e & 63;
#pragma unroll
      for (int mi = 0; mi < 4; ++mi) {
        int m = m0 + wr * 64 + mi * 16 + g * 4;
        int b = m >> 11;
        int n = m & (N_ - 1);
        ushort4v pk;
#pragma unroll
        for (int j = 0; j < 4; ++j) pk[j] = f2bf(acc[mi][ni][j]);
        *(ushort4v*)(VTw + ((size_t)(b * NH_ + h) * DH_ + d) * N_ + n) = pk;
      }
    }
  } else {
    ushort_t* dst = (kidx == 0) ? Qw : Kw;
    const float sc = (kidx == 0) ? QSCALE2_ : 1.0f;
#pragma unroll
    for (int ni = 0; ni < 4; ++ni) {
      int e = e0 + wc * 64 + ni * 16 + l15;
      int h = (e >> 6) & 15;
      int d = e & 63;
#pragma unroll
      for (int mi = 0; mi < 4; ++mi) {
#pragma unroll
        for (int j = 0; j < 4; ++j) {
          int m = m0 + wr * 64 + mi * 16 + g * 4 + j;
          int b = m >> 11;
          int n = m & (N_ - 1);
          dst[(size_t)((b * NH_ + h) * N_ + n) * DH_ + d] = f2bf(acc[mi][ni][j] * sc);
        }
      }
    }
  }
}

// ---------------------------------------------------------------- attention
// Block = (b,h) x 128 q-rows; 4 waves x 32 q (2 sub-tiles of 16).
// R7 post-mortem: 2-wave version was latency-bound (Occupancy 10.7%,
// MfmaUtil 11%, VALUBusy 41%) -> back to 4 waves; 51200B LDS + ~150 VGPR
// allows 3 blocks/CU = 12 waves/CU.  P-write was the 3.1M bank-conflict
// source (b32, 4-way across wave) -> packed ds_write_b64 (balanced 4-clk,
// conflict-free, half the instrs).  Swapped QK^T (S^T = K.Q^T, Q pre-scaled
// by SCALE*log2e).  Mask folded into Q-load.  K/VT XOR-swizzled (rule #21).
// Double-buffered 2-phase.  exp2-domain online softmax w/ defer-max (T13),
// max3 tree (T17), setprio (T5).  Grid 512, chunked XCD swizzle (T1).
__global__ __launch_bounds__(256)
void attn_kernel(const ushort_t* __restrict__ Qw,
                 const ushort_t* __restrict__ Kw,
                 const ushort_t* __restrict__ VTw,
                 const int* __restrict__ amask,
                 float* __restrict__ out) {
  // dbuf K(4096)+VT(4096) x2 = 16384 ush; P = 4w*32*72 = 9216 ush (51200 B)
  __shared__ ushort_t smem[16384 + 9216];
  ushort_t* lds_p = smem + 16384;

  const int tid = threadIdx.x;
  const int lane = tid & 63;
  const int w = tid >> 6;               // 0..3
  const int g = lane >> 4;
  const int l15 = lane & 15;
  const int wid = blockIdx.x;
  const int logical = (wid & 7) * 64 + (wid >> 3);  // XCD-chunked (bijective)
  const int bh = logical >> 4;
  const int b = bh >> 4, h = bh & 15;
  const int q0 = (logical & 15) * 128;

  const size_t base_nd = (size_t)bh * N_ * DH_;  // Q,K [n][64]
  const size_t base_dn = (size_t)bh * DH_ * N_;  // VT  [64][n]

  // per-wave q rows: q = q0 + w*32 + qi*16 + l15   (qi = 0..1)
  const bf16x8 qzero = {0, 0, 0, 0, 0, 0, 0, 0};
  bf16x8 qf[2][2];
#pragma unroll
  for (int qi = 0; qi < 2; ++qi) {
    int q = q0 + w * 32 + qi * 16 + l15;
    int mq = amask[b * N_ + q];  // faithful query-row mask
#pragma unroll
    for (int ks = 0; ks < 2; ++ks) {
      bf16x8 v = *(const bf16x8*)(Qw + base_nd + (size_t)q * DH_ + ks * 32 + g * 8);
      qf[qi][ks] = mq ? v : qzero;     // masked row -> all scores equal ->
    }                                  // uniform softmax == reference
  }

  // staging lane geometry (swizzled source, rule #21):
  const int st_r = (lane >> 3);              // row-within-chunk 0..7
  const int st_s = (lane & 7) ^ st_r;        // swizzled 16B col-slot

  f32x4 zero = {0.f, 0.f, 0.f, 0.f};
  f32x4 oacc[2][4];
#pragma unroll
  for (int qi = 0; qi < 2; ++qi)
#pragma unroll
    for (int df = 0; df < 4; ++df) oacc[qi][df] = zero;
  float m_run[2] = {-3.0e38f, -3.0e38f};
  float l_run[2] = {0.0f, 0.0f};

  const int NT = N_ / 64;

  // prologue: stage tile 0 into buf 0 (8 chunks per tile, 2 per wave)
  {
#pragma unroll
    for (int i = 0; i < 2; ++i) {
      int chunk = w * 2 + i;
      int r = chunk * 8 + st_r;
      GLOAD_LDS16(Kw + base_nd + (size_t)r * DH_ + st_s * 8, smem + chunk * 512);
      GLOAD_LDS16(VTw + base_dn + (size_t)r * N_ + st_s * 8, smem + 4096 + chunk * 512);
    }
  }
  __syncthreads();

  for (int it = 0; it < NT; ++it) {
    const int cur = it & 1;
    ushort_t* lk = smem + cur * 8192;
    ushort_t* lv = smem + 4096 + cur * 8192;

    // prefetch next tile into the other buffer (overlaps with this compute)
    if (it + 1 < NT) {
      const int kv0n = (it + 1) * 64;
      ushort_t* nk = smem + (cur ^ 1) * 8192;
      ushort_t* nv = nk + 4096;
#pragma unroll
      for (int i = 0; i < 2; ++i) {
        int chunk = w * 2 + i;
        int r = chunk * 8 + st_r;
        GLOAD_LDS16(Kw + base_nd + (size_t)(kv0n + r) * DH_ + st_s * 8, nk + chunk * 512);
        GLOAD_LDS16(VTw + base_dn + (size_t)r * N_ + kv0n + st_s * 8, nv + chunk * 512);
      }
    }

    // ---- QK^T: S^T = K . Q^T  (each K-frag read feeds both qi MFMAs)
    f32x4 sacc[2][4];
#pragma unroll
    for (int qi = 0; qi < 2; ++qi)
#pragma unroll
      for (int kvf = 0; kvf < 4; ++kvf) sacc[qi][kvf] = zero;
    __builtin_amdgcn_s_setprio(1);
#pragma unroll
    for (int ks = 0; ks < 2; ++ks) {
#pragma unroll
      for (int kvf = 0; kvf < 4; ++kvf) {
        bf16x8 a = *(const bf16x8*)(lk + (kvf * 16 + l15) * 64 +
                                    (((ks * 4 + g) ^ (l15 & 7)) * 8));
        sacc[0][kvf] = __builtin_amdgcn_mfma_f32_16x16x32_bf16(a, qf[0][ks], sacc[0][kvf], 0, 0, 0);
        sacc[1][kvf] = __builtin_amdgcn_mfma_f32_16x16x32_bf16(a, qf[1][ks], sacc[1][kvf], 0, 0, 0);
      }
    }
    __builtin_amdgcn_s_setprio(0);

    // ---- exp2-domain online softmax (kv reduce = 2 shfl_xor; defer-max)
    ushort_t* pw = lds_p + w * (32 * 72);
#pragma unroll
    for (int qi = 0; qi < 2; ++qi) {
      float a0 = max3f(sacc[qi][0][0], sacc[qi][0][1], sacc[qi][0][2]);
      float a1 = max3f(sacc[qi][0][3], sacc[qi][1][0], sacc[qi][1][1]);
      float a2 = max3f(sacc[qi][1][2], sacc[qi][1][3], sacc[qi][2][0]);
      float a3 = max3f(sacc[qi][2][1], sacc[qi][2][2], sacc[qi][2][3]);
      float a4 = max3f(sacc[qi][3][0], sacc[qi][3][1], sacc[qi][3][2]);
      float tm = fmaxf(max3f(a0, a1, a2), max3f(a3, a4, sacc[qi][3][3]));
      tm = fmaxf(tm, __shfl_xor(tm, 16));
      tm = fmaxf(tm, __shfl_xor(tm, 32));

      if (__any(tm > m_run[qi] + THR2_)) {   // defer-max: rescale rarely
        float m_new = fmaxf(m_run[qi], tm);
        float alpha = exp2f(m_run[qi] - m_new);
        l_run[qi] *= alpha;
#pragma unroll
        for (int df = 0; df < 4; ++df)
#pragma unroll
          for (int j = 0; j < 4; ++j) oacc[qi][df][j] *= alpha;
        m_run[qi] = m_new;
      }

      float p[16];
#pragma unroll
      for (int kvf = 0; kvf < 4; ++kvf)
#pragma unroll
        for (int j = 0; j < 4; ++j)
          p[kvf * 4 + j] = exp2f(sacc[qi][kvf][j] - m_run[qi]);
      float t0 = (p[0] + p[1]) + (p[2] + p[3]);
      float t1 = (p[4] + p[5]) + (p[6] + p[7]);
      float t2 = (p[8] + p[9]) + (p[10] + p[11]);
      float t3 = (p[12] + p[13]) + (p[14] + p[15]);
      float ps = (t0 + t1) + (t2 + t3);
      ps += __shfl_xor(ps, 16);
      ps += __shfl_xor(ps, 32);
      l_run[qi] += ps;

      // P -> wave-private LDS [q32][kv, stride 72] via packed b64 writes
      // (balanced across banks: 128 bank-accesses / 32 banks = 4-clk min;
      //  replaces the b32 pattern that cost 3.1M conflict cycles in R7)
#pragma unroll
      for (int kvf = 0; kvf < 4; ++kvf) {
        uint2v pkv;
        pkv[0] = pk2bf(p[kvf * 4 + 0], p[kvf * 4 + 1]);
        pkv[1] = pk2bf(p[kvf * 4 + 2], p[kvf * 4 + 3]);
        *(uint2v*)(pw + (qi * 16 + l15) * 72 + kvf * 16 + g * 4) = pkv;
      }
    }

    // ---- PV: O^T += VT . P^T  (each VT-frag read feeds both qi MFMAs)
    __builtin_amdgcn_s_setprio(1);
#pragma unroll
    for (int ks = 0; ks < 2; ++ks) {
      bf16x8 pb0 = *(const bf16x8*)(pw + (0 * 16 + l15) * 72 + ks * 32 + g * 8);
      bf16x8 pb1 = *(const bf16x8*)(pw + (1 * 16 + l15) * 72 + ks * 32 + g * 8);
#pragma unroll
      for (int df = 0; df < 4; ++df) {
        bf16x8 a = *(const bf16x8*)(lv + (df * 16 + l15) * 64 +
                                    (((ks * 4 + g) ^ (l15 & 7)) * 8));
        oacc[0][df] = __builtin_amdgcn_mfma_f32_16x16x32_bf16(a, pb0, oacc[0][df], 0, 0, 0);
        oacc[1][df] = __builtin_amdgcn_mfma_f32_16x16x32_bf16(a, pb1, oacc[1][df], 0, 0, 0);
      }
    }
    __builtin_amdgcn_s_setprio(0);
    __syncthreads();  // drains prefetch vmcnt + protects buffers
  }

  // epilogue: O^T/l -> LDS [q128][68] f32 -> coalesced global
  // (safe: loop-end __syncthreads ensures all waves finished P reads;
  //  osm footprint 128*68*4 = 34816 B < 51200 B)
  float inv[2] = {1.0f / l_run[0], 1.0f / l_run[1]};
  float* osm = (float*)smem;
#pragma unroll
  for (int qi = 0; qi < 2; ++qi)
#pragma unroll
    for (int df = 0; df < 4; ++df)
#pragma unroll
      for (int j = 0; j < 4; ++j)
        osm[(w * 32 + qi * 16 + l15) * 68 + df * 16 + g * 4 + j] = oacc[qi][df][j] * inv[qi];
  __syncthreads();
  // 256 threads, 128 rows: 2 passes of 64 rows; 4 lanes cover one row
  int d0 = (tid & 3) * 16;
#pragma unroll
  for (int rr = 0; rr < 2; ++rr) {
    int ql = rr * 64 + (tid >> 2);
    float* dst = out + ((size_t)(b * N_ + q0 + ql)) * H_ + h * DH_ + d0;
#pragma unroll
    for (int jj = 0; jj < 4; ++jj) {
      float4v v;
#pragma unroll
      for (int k = 0; k < 4; ++k) v[k] = osm[ql * 68 + d0 + jj * 4 + k];
      *(float4v*)(dst + jj * 4) = v;
    }
  }
}

// ---------------------------------------------------------------- launch
extern "C" void kernel_launch(void* const* d_in, const int* in_sizes, int n_in,
                              void* d_out, int out_size, void* d_ws, size_t ws_size,
                              hipStream_t stream) {
  const float* X = (const float*)d_in[0];
  const int* amask = (const int*)d_in[1];
  const float* Wq = (const float*)d_in[2];
  float* out = (float*)d_out;
  char* ws = (char*)d_ws;
  // ws layout (bytes): Xb 8M | Wb 6M | Q 8M | K 8M | VT 8M  = 38MB total
  ushort_t* Xb  = (ushort_t*)(ws);
  ushort_t* Wb  = (ushort_t*)(ws + 8388608);
  ushort_t* Qw  = (ushort_t*)(ws + 14680064);
  ushort_t* Kw  = (ushort_t*)(ws + 23068672);
  ushort_t* VTw = (ushort_t*)(ws + 31457280);

  convert_kernel<<<7168, 256, 0, stream>>>(X, Wq, Xb, Wb);
  gemm_qkv<<<768, 256, 0, stream>>>(Xb, Wb, Qw, Kw, VTw);
  attn_kernel<<<512, 256, 0, stream>>>(Qw, Kw, VTw, amask, out);
}

// Round 10
// 181.583 us; speedup vs baseline: 1.2236x; 1.0764x over previous
//
#include <hip/hip_runtime.h>
#include <hip/hip_bf16.h>
#include <stdint.h>

// B=2, N=2048, H=1024, NH=16, DH=64.
// SCALE = H^-0.5 = 1/32; softmax computed in exp2 domain, so Q is
// pre-scaled by SCALE*log2(e) at the GEMM epilogue.
#define B_ 2
#define N_ 2048
#define H_ 1024
#define NH_ 16
#define DH_ 64
#define E_ 3072
#define M_ 4096
#define K_ 1024
#define QSCALE2_ 0.0450842200277786f   /* (1/32) * log2(e) */
#define THR2_    11.5415603f           /* defer-max: 8 * log2(e) */

typedef unsigned short ushort_t;
typedef short bf16x8 __attribute__((ext_vector_type(8)));
typedef float f32x4 __attribute__((ext_vector_type(4)));
typedef ushort_t ushort8 __attribute__((ext_vector_type(8)));
typedef ushort_t ushort4v __attribute__((ext_vector_type(4)));
typedef float float4v __attribute__((ext_vector_type(4)));
typedef uint32_t uint2v __attribute__((ext_vector_type(2)));

// HW convert via plain cast (m240) + memcpy punning (ctor-safe).
static __device__ __forceinline__ ushort_t f2bf(float f) {
  __hip_bfloat16 h = __float2bfloat16(f);
  ushort_t u;
  __builtin_memcpy(&u, &h, sizeof(u));
  return u;
}
static __device__ __forceinline__ uint32_t pk2bf(float lo, float hi) {
  return (uint32_t)f2bf(lo) | ((uint32_t)f2bf(hi) << 16);
}
static __device__ __forceinline__ float max3f(float a, float b, float c) {
  return fmaxf(fmaxf(a, b), c);  // clang fuses to v_max3_f32
}

#define GLOAD_LDS16(g, l)                                                   \
  __builtin_amdgcn_global_load_lds(                                         \
      (const __attribute__((address_space(1))) void*)(g),                   \
      (__attribute__((address_space(3))) void*)(l), 16, 0, 0)

// ---------------------------------------------------------------- convert
// fp32 -> bf16 for X [4096,1024] and W [3072,1024]
__global__ void convert_kernel(const float* __restrict__ X,
                               const float* __restrict__ W,
                               ushort_t* __restrict__ Xb,
                               ushort_t* __restrict__ Wb) {
  const int nx4 = (M_ * K_) / 4;
  int i = blockIdx.x * blockDim.x + threadIdx.x;
  if (i < nx4) {
    float4v v = ((const float4v*)X)[i];
    ushort4v o;
    o[0] = f2bf(v[0]); o[1] = f2bf(v[1]); o[2] = f2bf(v[2]); o[3] = f2bf(v[3]);
    ((ushort4v*)Xb)[i] = o;
  } else {
    int j = i - nx4;  // grid sized exactly (nx4 + nw4 threads)
    float4v v = ((const float4v*)W)[j];
    ushort4v o;
    o[0] = f2bf(v[0]); o[1] = f2bf(v[1]); o[2] = f2bf(v[2]); o[3] = f2bf(v[3]);
    ((ushort4v*)Wb)[j] = o;
  }
}

// ---------------------------------------------------------------- QKV GEMM
// out[m,e] = sum_k X[m,k]*W[e,k].  m97 structure (128x128, BK=64, 4 waves,
// global_load_lds w16).  Epilogue: Q pre-scaled by SCALE*log2e -> [bh][n][d];
// K -> [bh][n][d]; V written TRANSPOSED -> VT [bh][d][n] with 8B vec stores.
// 1-D grid 768, chunked XCD swizzle (T1).
__global__ void gemm_qkv(const ushort_t* __restrict__ Xb,
                         const ushort_t* __restrict__ Wb,
                         ushort_t* __restrict__ Qw,
                         ushort_t* __restrict__ Kw,
                         ushort_t* __restrict__ VTw) {
  __shared__ ushort_t lds_a[128 * 64];
  __shared__ ushort_t lds_b[128 * 64];
  const int tid = threadIdx.x;
  const int lane = tid & 63;
  const int w = tid >> 6;
  const int g = lane >> 4;
  const int l15 = lane & 15;
  const int wid = blockIdx.x;
  const int logical = (wid & 7) * 96 + (wid >> 3);  // XCD-chunked (bijective)
  const int m0 = (logical / 24) * 128;
  const int e0 = (logical % 24) * 128;
  const int wr = w >> 1, wc = w & 1;

  f32x4 zero = {0.f, 0.f, 0.f, 0.f};
  f32x4 acc[4][4];
#pragma unroll
  for (int mi = 0; mi < 4; ++mi)
#pragma unroll
    for (int ni = 0; ni < 4; ++ni) acc[mi][ni] = zero;

  for (int kt = 0; kt < K_ / 64; ++kt) {
    const int k0 = kt * 64;
#pragma unroll
    for (int i = 0; i < 4; ++i) {
      int chunk = i * 4 + w;           // wave-uniform LDS dest
      int c = chunk * 64 + lane;       // 0..1023 16B-chunks
      int row = c >> 3;
      int col = (c & 7) * 8;
      GLOAD_LDS16(Xb + (size_t)(m0 + row) * K_ + k0 + col, lds_a + chunk * 512);
      GLOAD_LDS16(Wb + (size_t)(e0 + row) * K_ + k0 + col, lds_b + chunk * 512);
    }
    __syncthreads();
#pragma unroll
    for (int ks = 0; ks < 2; ++ks) {
      bf16x8 af[4], bfr[4];
#pragma unroll
      for (int mi = 0; mi < 4; ++mi)
        af[mi] = *(const bf16x8*)(lds_a + (wr * 64 + mi * 16 + l15) * 64 + ks * 32 + g * 8);
#pragma unroll
      for (int ni = 0; ni < 4; ++ni)
        bfr[ni] = *(const bf16x8*)(lds_b + (wc * 64 + ni * 16 + l15) * 64 + ks * 32 + g * 8);
#pragma unroll
      for (int mi = 0; mi < 4; ++mi)
#pragma unroll
        for (int ni = 0; ni < 4; ++ni)
          acc[mi][ni] = __builtin_amdgcn_mfma_f32_16x16x32_bf16(af[mi], bfr[ni], acc[mi][ni], 0, 0, 0);
    }
    __syncthreads();
  }

  // epilogue: C/D layout col=lane&15, row=(lane>>4)*4+j  [verified m89/m91]
  const int kidx = e0 >> 10;
  if (kidx == 2) {
    // V -> VT [bh][d][n], 4 consecutive n per thread -> 8B stores
#pragma unroll
    for (int ni = 0; ni < 4; ++ni) {
      int e = e0 + wc * 64 + ni * 16 + l15;
      int h = (e >> 6) & 15;
      int d = e & 63;
#pragma unroll
      for (int mi = 0; mi < 4; ++mi) {
        int m = m0 + wr * 64 + mi * 16 + g * 4;
        int b = m >> 11;
        int n = m & (N_ - 1);
        ushort4v pk;
#pragma unroll
        for (int j = 0; j < 4; ++j) pk[j] = f2bf(acc[mi][ni][j]);
        *(ushort4v*)(VTw + ((size_t)(b * NH_ + h) * DH_ + d) * N_ + n) = pk;
      }
    }
  } else {
    ushort_t* dst = (kidx == 0) ? Qw : Kw;
    const float sc = (kidx == 0) ? QSCALE2_ : 1.0f;
#pragma unroll
    for (int ni = 0; ni < 4; ++ni) {
      int e = e0 + wc * 64 + ni * 16 + l15;
      int h = (e >> 6) & 15;
      int d = e & 63;
#pragma unroll
      for (int mi = 0; mi < 4; ++mi) {
#pragma unroll
        for (int j = 0; j < 4; ++j) {
          int m = m0 + wr * 64 + mi * 16 + g * 4 + j;
          int b = m >> 11;
          int n = m & (N_ - 1);
          dst[(size_t)((b * NH_ + h) * N_ + n) * DH_ + d] = f2bf(acc[mi][ni][j] * sc);
        }
      }
    }
  }
}

// ---------------------------------------------------------------- attention
// Block = (b,h) x 128 q-rows; 8 waves x 16 q.  R9 post-mortem: grid 512 caps
// residency at 2 blocks/CU, so waves/CU was 8 (18.8% occupancy) and both
// pipes idle (latency-bound; LDS pipe only ~27% busy by arithmetic).  8-wave
// blocks double TLP to 16 waves/CU (4/SIMD) at ~1.6x LDS traffic — still
// under the LDS ceiling.  Swapped QK^T (S^T = K.Q^T, Q pre-scaled by
// SCALE*log2e).  Mask folded into Q-load.  K/VT XOR-swizzled (rule #21).
// Double-buffered 2-phase.  exp2-domain online softmax w/ defer-max (T13),
// max3 tree (T17), setprio (T5).  Grid 512, chunked XCD swizzle (T1).
__global__ __launch_bounds__(512)
void attn_kernel(const ushort_t* __restrict__ Qw,
                 const ushort_t* __restrict__ Kw,
                 const ushort_t* __restrict__ VTw,
                 const int* __restrict__ amask,
                 float* __restrict__ out) {
  // dbuf K(4096)+VT(4096) x2 = 16384 ush; P = 8w*16*72 = 9216 ush (51200 B)
  __shared__ ushort_t smem[16384 + 9216];
  ushort_t* lds_p = smem + 16384;

  const int tid = threadIdx.x;
  const int lane = tid & 63;
  const int w = tid >> 6;               // 0..7
  const int g = lane >> 4;
  const int l15 = lane & 15;
  const int wid = blockIdx.x;
  const int logical = (wid & 7) * 64 + (wid >> 3);  // XCD-chunked (bijective)
  const int bh = logical >> 4;
  const int b = bh >> 4, h = bh & 15;
  const int q0 = (logical & 15) * 128;

  const size_t base_nd = (size_t)bh * N_ * DH_;  // Q,K [n][64]
  const size_t base_dn = (size_t)bh * DH_ * N_;  // VT  [64][n]

  // per-wave q rows: q = q0 + w*16 + l15
  const bf16x8 qzero = {0, 0, 0, 0, 0, 0, 0, 0};
  bf16x8 qf[2];
  {
    int q = q0 + w * 16 + l15;
    int mq = amask[b * N_ + q];  // faithful query-row mask
#pragma unroll
    for (int ks = 0; ks < 2; ++ks) {
      bf16x8 v = *(const bf16x8*)(Qw + base_nd + (size_t)q * DH_ + ks * 32 + g * 8);
      qf[ks] = mq ? v : qzero;   // masked row -> all scores equal ->
    }                            // uniform softmax == reference
  }

  // staging lane geometry (swizzled source, rule #21):
  const int st_r = (lane >> 3);              // row-within-chunk 0..7
  const int st_s = (lane & 7) ^ st_r;        // swizzled 16B col-slot

  f32x4 zero = {0.f, 0.f, 0.f, 0.f};
  f32x4 oacc[4];
#pragma unroll
  for (int df = 0; df < 4; ++df) oacc[df] = zero;
  float m_run = -3.0e38f;
  float l_run = 0.0f;

  const int NT = N_ / 64;

  // prologue: stage tile 0 into buf 0 (8 chunks per tile, 1 per wave)
  {
    int r = w * 8 + st_r;
    GLOAD_LDS16(Kw + base_nd + (size_t)r * DH_ + st_s * 8, smem + w * 512);
    GLOAD_LDS16(VTw + base_dn + (size_t)r * N_ + st_s * 8, smem + 4096 + w * 512);
  }
  __syncthreads();

  for (int it = 0; it < NT; ++it) {
    const int cur = it & 1;
    ushort_t* lk = smem + cur * 8192;
    ushort_t* lv = smem + 4096 + cur * 8192;

    // prefetch next tile into the other buffer (overlaps with this compute)
    if (it + 1 < NT) {
      const int kv0n = (it + 1) * 64;
      ushort_t* nk = smem + (cur ^ 1) * 8192;
      ushort_t* nv = nk + 4096;
      int r = w * 8 + st_r;
      GLOAD_LDS16(Kw + base_nd + (size_t)(kv0n + r) * DH_ + st_s * 8, nk + w * 512);
      GLOAD_LDS16(VTw + base_dn + (size_t)r * N_ + kv0n + st_s * 8, nv + w * 512);
    }

    // ---- QK^T: S^T = K . Q^T
    f32x4 sacc[4];
#pragma unroll
    for (int kvf = 0; kvf < 4; ++kvf) sacc[kvf] = zero;
    __builtin_amdgcn_s_setprio(1);
#pragma unroll
    for (int ks = 0; ks < 2; ++ks) {
#pragma unroll
      for (int kvf = 0; kvf < 4; ++kvf) {
        bf16x8 a = *(const bf16x8*)(lk + (kvf * 16 + l15) * 64 +
                                    (((ks * 4 + g) ^ (l15 & 7)) * 8));
        sacc[kvf] = __builtin_amdgcn_mfma_f32_16x16x32_bf16(a, qf[ks], sacc[kvf], 0, 0, 0);
      }
    }
    __builtin_amdgcn_s_setprio(0);

    // ---- exp2-domain online softmax (kv reduce = 2 shfl_xor; defer-max)
    ushort_t* pw = lds_p + w * (16 * 72);
    {
      float a0 = max3f(sacc[0][0], sacc[0][1], sacc[0][2]);
      float a1 = max3f(sacc[0][3], sacc[1][0], sacc[1][1]);
      float a2 = max3f(sacc[1][2], sacc[1][3], sacc[2][0]);
      float a3 = max3f(sacc[2][1], sacc[2][2], sacc[2][3]);
      float a4 = max3f(sacc[3][0], sacc[3][1], sacc[3][2]);
      float tm = fmaxf(max3f(a0, a1, a2), max3f(a3, a4, sacc[3][3]));
      tm = fmaxf(tm, __shfl_xor(tm, 16));
      tm = fmaxf(tm, __shfl_xor(tm, 32));

      if (__any(tm > m_run + THR2_)) {   // defer-max: rescale rarely
        float m_new = fmaxf(m_run, tm);
        float alpha = exp2f(m_run - m_new);
        l_run *= alpha;
#pragma unroll
        for (int df = 0; df < 4; ++df)
#pragma unroll
          for (int j = 0; j < 4; ++j) oacc[df][j] *= alpha;
        m_run = m_new;
      }

      float p[16];
#pragma unroll
      for (int kvf = 0; kvf < 4; ++kvf)
#pragma unroll
        for (int j = 0; j < 4; ++j)
          p[kvf * 4 + j] = exp2f(sacc[kvf][j] - m_run);
      float t0 = (p[0] + p[1]) + (p[2] + p[3]);
      float t1 = (p[4] + p[5]) + (p[6] + p[7]);
      float t2 = (p[8] + p[9]) + (p[10] + p[11]);
      float t3 = (p[12] + p[13]) + (p[14] + p[15]);
      float ps = (t0 + t1) + (t2 + t3);
      ps += __shfl_xor(ps, 16);
      ps += __shfl_xor(ps, 32);
      l_run += ps;

      // P -> wave-private LDS [q16][kv, stride 72] via packed b64 writes
#pragma unroll
      for (int kvf = 0; kvf < 4; ++kvf) {
        uint2v pkv;
        pkv[0] = pk2bf(p[kvf * 4 + 0], p[kvf * 4 + 1]);
        pkv[1] = pk2bf(p[kvf * 4 + 2], p[kvf * 4 + 3]);
        *(uint2v*)(pw + l15 * 72 + kvf * 16 + g * 4) = pkv;
      }
    }

    // ---- PV: O^T += VT . P^T
    __builtin_amdgcn_s_setprio(1);
#pragma unroll
    for (int ks = 0; ks < 2; ++ks) {
      bf16x8 pb = *(const bf16x8*)(pw + l15 * 72 + ks * 32 + g * 8);
#pragma unroll
      for (int df = 0; df < 4; ++df) {
        bf16x8 a = *(const bf16x8*)(lv + (df * 16 + l15) * 64 +
                                    (((ks * 4 + g) ^ (l15 & 7)) * 8));
        oacc[df] = __builtin_amdgcn_mfma_f32_16x16x32_bf16(a, pb, oacc[df], 0, 0, 0);
      }
    }
    __builtin_amdgcn_s_setprio(0);
    __syncthreads();  // drains prefetch vmcnt + protects buffers
  }

  // epilogue: O^T/l -> LDS [q128][68] f32 -> coalesced global
  // (osm footprint 128*68*4 = 34816 B < 51200 B)
  float inv = 1.0f / l_run;
  float* osm = (float*)smem;
#pragma unroll
  for (int df = 0; df < 4; ++df)
#pragma unroll
    for (int j = 0; j < 4; ++j)
      osm[(w * 16 + l15) * 68 + df * 16 + g * 4 + j] = oacc[df][j] * inv;
  __syncthreads();
  // 512 threads, 128 rows: single pass; 4 lanes cover one row
  int d0 = (tid & 3) * 16;
  int ql = tid >> 2;
  float* dst = out + ((size_t)(b * N_ + q0 + ql)) * H_ + h * DH_ + d0;
#pragma unroll
  for (int jj = 0; jj < 4; ++jj) {
    float4v v;
#pragma unroll
    for (int k = 0; k < 4; ++k) v[k] = osm[ql * 68 + d0 + jj * 4 + k];
    *(float4v*)(dst + jj * 4) = v;
  }
}

// ---------------------------------------------------------------- launch
extern "C" void kernel_launch(void* const* d_in, const int* in_sizes, int n_in,
                              void* d_out, int out_size, void* d_ws, size_t ws_size,
                              hipStream_t stream) {
  const float* X = (const float*)d_in[0];
  const int* amask = (const int*)d_in[1];
  const float* Wq = (const float*)d_in[2];
  float* out = (float*)d_out;
  char* ws = (char*)d_ws;
  // ws layout (bytes): Xb 8M | Wb 6M | Q 8M | K 8M | VT 8M  = 38MB total
  ushort_t* Xb  = (ushort_t*)(ws);
  ushort_t* Wb  = (ushort_t*)(ws + 8388608);
  ushort_t* Qw  = (ushort_t*)(ws + 14680064);
  ushort_t* Kw  = (ushort_t*)(ws + 23068672);
  ushort_t* VTw = (ushort_t*)(ws + 31457280);

  convert_kernel<<<7168, 256, 0, stream>>>(X, Wq, Xb, Wb);
  gemm_qkv<<<768, 256, 0, stream>>>(Xb, Wb, Qw, Kw, VTw);
  attn_kernel<<<512, 512, 0, stream>>>(Qw, Kw, VTw, amask, out);
}